// Round 15
// baseline (10759.902 us; speedup 1.0000x reference)
//
#include <hip/hip_runtime.h>

#define SEQL 512
#define BSZ  32
#define HID  1024
#define NWORK 48
#define NLAUNCH 384
#define HN_OFF 16777216   // 32*512*1024

// ws layout (bytes): xps f16 [512][32][1024] @0 (32MB, overwritten in place with xp1);
// h0b bf16 @32MB (32MB); flags @64MB: 3 sets x [512][16] x 128B = 3MB;
// boot @67MB (17 ints). Total ~67.1MB (h1 state lives in d_out).
#define XPS_OFF 0u
#define H0B_OFF 33554432u
#define FLG_OFF 67108864u
#define BOOT_OFF 70254592u

#define FLSTRIDE 32          // u32s per flag slot (128B line per flag)
#define FLSET (SEQL * 16 * FLSTRIDE)   // u32s per flag set

using f32x4  = __attribute__((ext_vector_type(4))) float;
using u16x8  = __attribute__((ext_vector_type(8))) unsigned short;
using u32x4  = __attribute__((ext_vector_type(4))) unsigned int;
using bf16x8 = __attribute__((ext_vector_type(8))) __bf16;

__device__ __forceinline__ f32x4 mfma16(u16x8 a, u16x8 b, f32x4 c) {
  return __builtin_amdgcn_mfma_f32_16x16x32_bf16(
      __builtin_bit_cast(bf16x8, a), __builtin_bit_cast(bf16x8, b), c, 0, 0, 0);
}

__device__ __forceinline__ unsigned short f2bf(float f) {
  unsigned u = __builtin_bit_cast(unsigned, f);
  u += 0x7fffu + ((u >> 16) & 1u);
  return (unsigned short)(u >> 16);
}
__device__ __forceinline__ unsigned short f2h(float f) {
  _Float16 h = (_Float16)f;
  return __builtin_bit_cast(unsigned short, h);
}
__device__ __forceinline__ float h2f(unsigned short u) {
  return (float)__builtin_bit_cast(_Float16, u);
}

__device__ __forceinline__ float tanh_fast(float x) {
  float cx = fminf(fmaxf(x, -15.f), 15.f);
  float e = __expf(2.f * cx);
  return __fdividef(e - 1.f, e + 1.f);
}

// ---- flags: per-(t,producer) PRIVATE 128B line (single writer -> no false
// sharing / lost updates). Fast publish: plain WB store (lands in the shared
// XCD L2 — r5/r8/r13-proven for data). Backup: agent-scope atomic (MALL,
// proven rounds 2-13). Consumer: bounded sc0 poll window (L2-served), then
// proven agent fallback. Liveness unconditional.
__device__ __forceinline__ void flag_pub(unsigned* p) {
  unsigned one = 1u;
  asm volatile("global_store_dword %0, %1, off" :: "v"(p), "v"(one) : "memory");
  __hip_atomic_store(p, 1u, __ATOMIC_RELAXED, __HIP_MEMORY_SCOPE_AGENT);
}
__device__ __forceinline__ unsigned flag_get_agent(const unsigned* p) {
  return __hip_atomic_load(p, __ATOMIC_RELAXED, __HIP_MEMORY_SCOPE_AGENT);
}
__device__ __forceinline__ unsigned flag_get_sc0(const unsigned* p) {
  unsigned v;
  asm volatile("global_load_dword %0, %1, off sc0\n\ts_waitcnt vmcnt(0)"
               : "=&v"(v) : "v"(p) : "memory");
  return v;
}

// WG-level wait: wave 0 polls; lane i (i<16) watches producer i's private
// line. Bounded sc0 window (~128 polls) then agent fallback; __syncthreads
// releases the other waves.
__device__ __forceinline__ void wg_wait16(const unsigned* flt, int tid) {
  if (tid < 64) {
    const unsigned* p = flt + (tid & 15) * FLSTRIDE;
    int found = 0;
    for (int it = 0; it < 128 && !found; ++it)
      found = __all(flag_get_sc0(p) != 0u);
    if (!found) {
      while (!__all(flag_get_agent(p) != 0u)) __builtin_amdgcn_s_sleep(1);
    }
  }
  __syncthreads();
}
__device__ __forceinline__ void wg_wait1(const unsigned* p, int tid) {
  if (tid < 64) {
    int found = 0;
    for (int it = 0; it < 128 && !found; ++it)
      found = __all(flag_get_sc0(p) != 0u);
    if (!found) {
      while (!__all(flag_get_agent(p) != 0u)) __builtin_amdgcn_s_sleep(1);
    }
  }
  __syncthreads();
}

__global__ void init_kernel(unsigned* flg, int* boot) {
  int i = blockIdx.x * 256 + threadIdx.x;   // 3072*256 = 786432 = 3*FLSET
  if (i < 3 * FLSET) flg[i] = 0u;
  if (blockIdx.x == 0 && threadIdx.x < 17)
    boot[threadIdx.x] = (threadIdx.x == 16) ? -1 : 0;
}

// -------- xproj GEMM (layer 0): xps[s*32+b][h] = x[b][s][:]·W_ih0^T + b_ih0 + b_hh0 (f16 out)
__global__ __launch_bounds__(256, 2)
void xproj_gemm(const float* __restrict__ X,
                const float* __restrict__ W,
                const float* __restrict__ bih,
                const float* __restrict__ bhh,
                unsigned short* __restrict__ out)
{
  __shared__ unsigned short sA[128 * 32];
  __shared__ unsigned short sB[128 * 32];
  const int tid  = threadIdx.x;
  const int lane = tid & 63;
  const int wave = tid >> 6;
  const int wm = wave >> 1, wn = wave & 1;
  const int bm = blockIdx.x >> 3;
  const int bn = blockIdx.x & 7;
  const int l15 = lane & 15;
  const int koff = (lane >> 4) * 8;
  const int srow = tid >> 2;
  const int skc  = (tid & 3) * 8;

  f32x4 acc[4][4];
#pragma unroll
  for (int i = 0; i < 4; ++i)
#pragma unroll
    for (int j = 0; j < 4; ++j) acc[i][j] = (f32x4)0.f;

  for (int k0 = 0; k0 < HID; k0 += 32) {
#pragma unroll
    for (int r = 0; r < 2; ++r) {
      int row = r * 64 + srow;
      int Mrow = bm * 128 + row;
      const float* src = X + ((size_t)(Mrow & 31) * SEQL + (Mrow >> 5)) * HID + k0 + skc;
      float4 a = ((const float4*)src)[0];
      float4 b = ((const float4*)src)[1];
      u16x8 av;
      av[0]=f2bf(a.x); av[1]=f2bf(a.y); av[2]=f2bf(a.z); av[3]=f2bf(a.w);
      av[4]=f2bf(b.x); av[5]=f2bf(b.y); av[6]=f2bf(b.z); av[7]=f2bf(b.w);
      *(u16x8*)&sA[row * 32 + skc] = av;

      const float* wsrc = W + (size_t)(bn * 128 + row) * HID + k0 + skc;
      float4 wa = ((const float4*)wsrc)[0];
      float4 wb = ((const float4*)wsrc)[1];
      u16x8 wv;
      wv[0]=f2bf(wa.x); wv[1]=f2bf(wa.y); wv[2]=f2bf(wa.z); wv[3]=f2bf(wa.w);
      wv[4]=f2bf(wb.x); wv[5]=f2bf(wb.y); wv[6]=f2bf(wb.z); wv[7]=f2bf(wb.w);
      *(u16x8*)&sB[row * 32 + skc] = wv;
    }
    __syncthreads();

    u16x8 af[4], bfr[4];
#pragma unroll
    for (int mt = 0; mt < 4; ++mt)
      af[mt] = *(const u16x8*)&sA[(wm * 64 + mt * 16 + l15) * 32 + koff];
#pragma unroll
    for (int nt = 0; nt < 4; ++nt)
      bfr[nt] = *(const u16x8*)&sB[(wn * 64 + nt * 16 + l15) * 32 + koff];
#pragma unroll
    for (int mt = 0; mt < 4; ++mt)
#pragma unroll
      for (int nt = 0; nt < 4; ++nt)
        acc[mt][nt] = mfma16(af[mt], bfr[nt], acc[mt][nt]);
    __syncthreads();
  }

#pragma unroll
  for (int nt = 0; nt < 4; ++nt) {
    int colg = bn * 128 + wn * 64 + nt * 16 + l15;
    float bias = bih[colg] + bhh[colg];
#pragma unroll
    for (int mt = 0; mt < 4; ++mt) {
#pragma unroll
      for (int i = 0; i < 4; ++i) {
        int rowg = bm * 128 + wm * 64 + mt * 16 + (lane >> 4) * 4 + i;
        out[(size_t)rowg * HID + colg] = f2h(acc[mt][nt][i] + bias);
      }
    }
  }
}

// -------- fused 3-stage scan on ONE XCD: private-line L2-local flags --------
// S0 (role 0..15):  h0[t] = tanh(xps[t] + h0[t-1]·W_hh0^T) -> h0b, flag flA
// S1 (role 16..31): xp1[t] = h0[t]·W_ih1^T + b1 -> xps[t] slot (f16), flag flB
// S2 (role 32..47): h1[t] = tanh(xp1[t] + h1[t-1]·W_hh1^T) -> out (f32), flag flC
// Data: plain WB stores + plain cached loads (r13-proven). S2 reads h1[t-1]
// from d_out f32 (r3-proven path) — h1b eliminated to make room for flags.
__global__ __launch_bounds__(256, 2)
void fused_scan(unsigned short* __restrict__ xps,   // f16 [512][32][1024], in-place xp1
                const float* __restrict__ whh0,
                const float* __restrict__ wih1,
                const float* __restrict__ whh1,
                const float* __restrict__ bih1,
                const float* __restrict__ bhh1,
                unsigned short* __restrict__ h0b,
                float* __restrict__ out,
                unsigned* __restrict__ flg,
                int* __restrict__ boot)
{
  const int tid  = threadIdx.x;

  // ---- XCD-colocation bootstrap (proven rounds 5-14) ----
  __shared__ int s_role;
  if (tid == 0) {
    unsigned xcc;
    asm volatile("s_getreg_b32 %0, hwreg(HW_REG_XCC_ID)" : "=s"(xcc));
    xcc &= 15u;
    int slot = __hip_atomic_fetch_add(&boot[(int)xcc], 1, __ATOMIC_RELAXED,
                                      __HIP_MEMORY_SCOPE_AGENT);
    if (slot == NWORK - 1) {
      int exp = -1;
      __hip_atomic_compare_exchange_strong(&boot[16], &exp, (int)xcc,
          __ATOMIC_RELAXED, __ATOMIC_RELAXED, __HIP_MEMORY_SCOPE_AGENT);
    }
    int ch;
    while ((ch = __hip_atomic_load(&boot[16], __ATOMIC_RELAXED,
                                   __HIP_MEMORY_SCOPE_AGENT)) < 0)
      __builtin_amdgcn_s_sleep(8);
    s_role = ((int)xcc == ch && slot < NWORK) ? slot : -1;
  }
  __syncthreads();
  const int role = s_role;
  if (role < 0) return;

  const int lane = tid & 63;
  const int wave = tid >> 6;
  const int l15  = lane & 15;
  const int l4   = lane >> 4;
  const int stage = role >> 4;
  const int wg    = role & 15;
  const int col0  = wg * 64;
  const int kbase = wave * 256;
  const int frow  = tid >> 3;        // 0..31 batch row (finish phase)
  const int fcb   = (tid & 7) * 8;   // col offset within 64-col slice

  unsigned* flA = flg;
  unsigned* flB = flg + FLSET;
  unsigned* flC = flg + 2 * FLSET;

  __shared__ float red[4][32][68];

  // persistent weight fragments (f32 -> bf16), 128 VGPRs
  const float* Wsl = (stage == 0) ? whh0 : (stage == 1) ? wih1 : whh1;
  u16x8 Bf[4][8];
#pragma unroll
  for (int nt = 0; nt < 4; ++nt)
#pragma unroll
    for (int ks = 0; ks < 8; ++ks) {
      const float* src = Wsl + (size_t)(col0 + nt * 16 + l15) * HID + kbase + ks * 32 + l4 * 8;
      float4 a = ((const float4*)src)[0];
      float4 b = ((const float4*)src)[1];
      u16x8 v;
      v[0]=f2bf(a.x); v[1]=f2bf(a.y); v[2]=f2bf(a.z); v[3]=f2bf(a.w);
      v[4]=f2bf(b.x); v[5]=f2bf(b.y); v[6]=f2bf(b.z); v[7]=f2bf(b.w);
      Bf[nt][ks] = v;
    }

  if (stage == 0) {
    u16x8 xh = *(const u16x8*)(xps + (size_t)frow * HID + col0 + fcb);
    for (int t = 0; t < SEQL; ++t) {
      f32x4 acc[2][4];
#pragma unroll
      for (int m = 0; m < 2; ++m)
#pragma unroll
        for (int n = 0; n < 4; ++n) acc[m][n] = (f32x4)0.f;
      if (t > 0) {
        wg_wait16(flA + (size_t)(t - 1) * 16 * FLSTRIDE, tid);
        const unsigned short* hp = h0b + (size_t)(t - 1) * (BSZ * HID);
        u16x8 Af[2][8];
#pragma unroll
        for (int m = 0; m < 2; ++m)
#pragma unroll
          for (int ks = 0; ks < 8; ++ks)
            Af[m][ks] = *(const u16x8*)(hp + (size_t)(m * 16 + l15) * HID + kbase + ks * 32 + l4 * 8);
#pragma unroll
        for (int ks = 0; ks < 8; ++ks)
#pragma unroll
          for (int m = 0; m < 2; ++m)
#pragma unroll
            for (int n = 0; n < 4; ++n)
              acc[m][n] = mfma16(Af[m][ks], Bf[n][ks], acc[m][n]);
      }
#pragma unroll
      for (int m = 0; m < 2; ++m)
#pragma unroll
        for (int n = 0; n < 4; ++n)
#pragma unroll
          for (int q = 0; q < 4; ++q)
            red[wave][m * 16 + l4 * 4 + q][n * 16 + l15] = acc[m][n][q];
      __syncthreads();
      float hv[8];
#pragma unroll
      for (int jj = 0; jj < 2; ++jj) {
        float4 r0 = *(const float4*)&red[0][frow][fcb + jj * 4];
        float4 r1 = *(const float4*)&red[1][frow][fcb + jj * 4];
        float4 r2 = *(const float4*)&red[2][frow][fcb + jj * 4];
        float4 r3 = *(const float4*)&red[3][frow][fcb + jj * 4];
        hv[jj*4+0] = r0.x + r1.x + r2.x + r3.x;
        hv[jj*4+1] = r0.y + r1.y + r2.y + r3.y;
        hv[jj*4+2] = r0.z + r1.z + r2.z + r3.z;
        hv[jj*4+3] = r0.w + r1.w + r2.w + r3.w;
      }
#pragma unroll
      for (int j = 0; j < 8; ++j) hv[j] = tanh_fast(hv[j] + h2f((unsigned short)xh[j]));
      u16x8 hb;
#pragma unroll
      for (int j = 0; j < 8; ++j) hb[j] = f2bf(hv[j]);
      *(u16x8*)(h0b + (size_t)t * (BSZ * HID) + (size_t)frow * HID + col0 + fcb) = hb;
      if (t == SEQL - 1) {
        float* o = out + HN_OFF + (size_t)frow * HID + col0 + fcb;
        ((float4*)o)[0] = make_float4(hv[0], hv[1], hv[2], hv[3]);
        ((float4*)o)[1] = make_float4(hv[4], hv[5], hv[6], hv[7]);
      } else {
        xh = *(const u16x8*)(xps + ((size_t)(t + 1) * BSZ + frow) * HID + col0 + fcb);
      }
      asm volatile("s_waitcnt vmcnt(0)" ::: "memory");   // data acked at L2
      __syncthreads();
      if (tid == 0) flag_pub(&flA[((size_t)t * 16 + wg) * FLSTRIDE]);
    }
  } else if (stage == 1) {
    float bia[8];
#pragma unroll
    for (int j = 0; j < 8; ++j)
      bia[j] = bih1[col0 + fcb + j] + bhh1[col0 + fcb + j];
    for (int t = 0; t < SEQL; ++t) {
      wg_wait16(flA + (size_t)t * 16 * FLSTRIDE, tid);
      const unsigned short* hp = h0b + (size_t)t * (BSZ * HID);
      u16x8 Af[2][8];
#pragma unroll
      for (int m = 0; m < 2; ++m)
#pragma unroll
        for (int ks = 0; ks < 8; ++ks)
          Af[m][ks] = *(const u16x8*)(hp + (size_t)(m * 16 + l15) * HID + kbase + ks * 32 + l4 * 8);
      f32x4 acc[2][4];
#pragma unroll
      for (int m = 0; m < 2; ++m)
#pragma unroll
        for (int n = 0; n < 4; ++n) acc[m][n] = (f32x4)0.f;
#pragma unroll
      for (int ks = 0; ks < 8; ++ks)
#pragma unroll
        for (int m = 0; m < 2; ++m)
#pragma unroll
          for (int n = 0; n < 4; ++n)
            acc[m][n] = mfma16(Af[m][ks], Bf[n][ks], acc[m][n]);
#pragma unroll
      for (int m = 0; m < 2; ++m)
#pragma unroll
        for (int n = 0; n < 4; ++n)
#pragma unroll
          for (int q = 0; q < 4; ++q)
            red[wave][m * 16 + l4 * 4 + q][n * 16 + l15] = acc[m][n][q];
      __syncthreads();
      float sv[8];
#pragma unroll
      for (int jj = 0; jj < 2; ++jj) {
        float4 r0 = *(const float4*)&red[0][frow][fcb + jj * 4];
        float4 r1 = *(const float4*)&red[1][frow][fcb + jj * 4];
        float4 r2 = *(const float4*)&red[2][frow][fcb + jj * 4];
        float4 r3 = *(const float4*)&red[3][frow][fcb + jj * 4];
        sv[jj*4+0] = r0.x + r1.x + r2.x + r3.x;
        sv[jj*4+1] = r0.y + r1.y + r2.y + r3.y;
        sv[jj*4+2] = r0.z + r1.z + r2.z + r3.z;
        sv[jj*4+3] = r0.w + r1.w + r2.w + r3.w;
      }
      u16x8 xo;
#pragma unroll
      for (int j = 0; j < 8; ++j) xo[j] = f2h(sv[j] + bia[j]);
      *(u16x8*)(xps + ((size_t)t * BSZ + frow) * HID + col0 + fcb) = xo;
      asm volatile("s_waitcnt vmcnt(0)" ::: "memory");
      __syncthreads();
      if (tid == 0) flag_pub(&flB[((size_t)t * 16 + wg) * FLSTRIDE]);
    }
  } else {
    for (int t = 0; t < SEQL; ++t) {
      f32x4 acc[2][4];
#pragma unroll
      for (int m = 0; m < 2; ++m)
#pragma unroll
        for (int n = 0; n < 4; ++n) acc[m][n] = (f32x4)0.f;
      if (t > 0) {
        wg_wait16(flC + (size_t)(t - 1) * 16 * FLSTRIDE, tid);
        // read h1[t-1] from out (f32, [bs][seq][H]) — r3-proven path
        u16x8 Af[2][8];
#pragma unroll
        for (int m = 0; m < 2; ++m)
#pragma unroll
          for (int ks = 0; ks < 8; ++ks) {
            const float* src = out + ((size_t)(m * 16 + l15) * SEQL + (t - 1)) * HID + kbase + ks * 32 + l4 * 8;
            float4 a = ((const float4*)src)[0];
            float4 b = ((const float4*)src)[1];
            u16x8 v;
            v[0]=f2bf(a.x); v[1]=f2bf(a.y); v[2]=f2bf(a.z); v[3]=f2bf(a.w);
            v[4]=f2bf(b.x); v[5]=f2bf(b.y); v[6]=f2bf(b.z); v[7]=f2bf(b.w);
            Af[m][ks] = v;
          }
#pragma unroll
        for (int ks = 0; ks < 8; ++ks)
#pragma unroll
          for (int m = 0; m < 2; ++m)
#pragma unroll
            for (int n = 0; n < 4; ++n)
              acc[m][n] = mfma16(Af[m][ks], Bf[n][ks], acc[m][n]);
      }
#pragma unroll
      for (int m = 0; m < 2; ++m)
#pragma unroll
        for (int n = 0; n < 4; ++n)
#pragma unroll
          for (int q = 0; q < 4; ++q)
            red[wave][m * 16 + l4 * 4 + q][n * 16 + l15] = acc[m][n][q];
      __syncthreads();
      wg_wait1(&flB[((size_t)t * 16 + wg) * FLSTRIDE], tid);
      u16x8 xq = *(const u16x8*)(xps + ((size_t)t * BSZ + frow) * HID + col0 + fcb);
      float hv[8];
#pragma unroll
      for (int jj = 0; jj < 2; ++jj) {
        float4 r0 = *(const float4*)&red[0][frow][fcb + jj * 4];
        float4 r1 = *(const float4*)&red[1][frow][fcb + jj * 4];
        float4 r2 = *(const float4*)&red[2][frow][fcb + jj * 4];
        float4 r3 = *(const float4*)&red[3][frow][fcb + jj * 4];
        hv[jj*4+0] = r0.x + r1.x + r2.x + r3.x;
        hv[jj*4+1] = r0.y + r1.y + r2.y + r3.y;
        hv[jj*4+2] = r0.z + r1.z + r2.z + r3.z;
        hv[jj*4+3] = r0.w + r1.w + r2.w + r3.w;
      }
#pragma unroll
      for (int j = 0; j < 8; ++j) hv[j] = tanh_fast(hv[j] + h2f((unsigned short)xq[j]));
      float* op = out + ((size_t)frow * SEQL + t) * HID + col0 + fcb;
      ((float4*)op)[0] = make_float4(hv[0], hv[1], hv[2], hv[3]);
      ((float4*)op)[1] = make_float4(hv[4], hv[5], hv[6], hv[7]);
      if (t == SEQL - 1) {
        float* o = out + HN_OFF + BSZ * HID + (size_t)frow * HID + col0 + fcb;
        ((float4*)o)[0] = make_float4(hv[0], hv[1], hv[2], hv[3]);
        ((float4*)o)[1] = make_float4(hv[4], hv[5], hv[6], hv[7]);
      }
      asm volatile("s_waitcnt vmcnt(0)" ::: "memory");
      __syncthreads();
      if (tid == 0) flag_pub(&flC[((size_t)t * 16 + wg) * FLSTRIDE]);
    }
  }
}

extern "C" void kernel_launch(void* const* d_in, const int* in_sizes, int n_in,
                              void* d_out, int out_size, void* d_ws, size_t ws_size,
                              hipStream_t stream) {
  const float* x    = (const float*)d_in[0];
  const float* w_ih = (const float*)d_in[1];
  const float* w_hh = (const float*)d_in[2];
  const float* b_ih = (const float*)d_in[3];
  const float* b_hh = (const float*)d_in[4];
  float* out = (float*)d_out;
  char* ws = (char*)d_ws;

  unsigned short* xps = (unsigned short*)(ws + XPS_OFF);
  unsigned short* h0b = (unsigned short*)(ws + H0B_OFF);
  unsigned* flg       = (unsigned*)(ws + FLG_OFF);
  int* boot           = (int*)(ws + BOOT_OFF);

  init_kernel<<<3072, 256, 0, stream>>>(flg, boot);
  xproj_gemm<<<1024, 256, 0, stream>>>(x, w_ih, b_ih, b_hh, xps);
  fused_scan<<<NLAUNCH, 256, 0, stream>>>(xps, w_hh,
      w_ih + (size_t)HID * HID, w_hh + (size_t)HID * HID,
      b_ih + HID, b_hh + HID, h0b, out, flg, boot);
}

// Round 16
// 4703.437 us; speedup vs baseline: 2.2877x; 2.2877x over previous
//
#include <hip/hip_runtime.h>

#define SEQL 512
#define BSZ  32
#define HID  1024
#define NWORK 32
#define NLAUNCH 384
#define HN_OFF 16777216   // 32*512*1024

// ws layout (bytes): xps f16 [512][32][1024] @0 (32MB, read-only in scan);
// h0b bf16 @32MB (32MB, sentinel); h1b bf16 @64MB (32MB, sentinel);
// boot @96MB (17 ints). Total ~96MB (proven ws >= 100.7MB).
#define XPS_OFF 0u
#define H0B_OFF 33554432u
#define H1B_OFF 67108864u
#define BOOT_OFF 100663296u

#define SENT32 0xAAAAAAAAu

using f32x4  = __attribute__((ext_vector_type(4))) float;
using u16x8  = __attribute__((ext_vector_type(8))) unsigned short;
using u32x4  = __attribute__((ext_vector_type(4))) unsigned int;
using u64x2  = __attribute__((ext_vector_type(2))) unsigned long long;
using bf16x8 = __attribute__((ext_vector_type(8))) __bf16;

__device__ __forceinline__ f32x4 mfma16(u16x8 a, u16x8 b, f32x4 c) {
  return __builtin_amdgcn_mfma_f32_16x16x32_bf16(
      __builtin_bit_cast(bf16x8, a), __builtin_bit_cast(bf16x8, b), c, 0, 0, 0);
}

__device__ __forceinline__ unsigned short f2bf(float f) {
  unsigned u = __builtin_bit_cast(unsigned, f);
  u += 0x7fffu + ((u >> 16) & 1u);
  return (unsigned short)(u >> 16);
}
__device__ __forceinline__ unsigned short f2h(float f) {
  _Float16 h = (_Float16)f;
  return __builtin_bit_cast(unsigned short, h);
}
__device__ __forceinline__ float h2f(unsigned short u) {
  return (float)__builtin_bit_cast(_Float16, u);
}

__device__ __forceinline__ float tanh_fast(float x) {
  float cx = fminf(fmaxf(x, -15.f), 15.f);
  float e = __expf(2.f * cx);
  return __fdividef(e - 1.f, e + 1.f);
}

// ---- agent-scope 8B primitives (the ONLY proven cross-CU visibility pair:
// rounds 2-15 flags; r2 read xproj data this way and passed)
__device__ __forceinline__ unsigned long long ld8_agent(const unsigned long long* p) {
  return __hip_atomic_load(p, __ATOMIC_RELAXED, __HIP_MEMORY_SCOPE_AGENT);
}
__device__ __forceinline__ void st8_agent(unsigned long long* p, unsigned long long v) {
  __hip_atomic_store(p, v, __ATOMIC_RELAXED, __HIP_MEMORY_SCOPE_AGENT);
}
// store one u16x8 (16B) as two agent 8B stores
__device__ __forceinline__ void st_frag(unsigned short* dst, u16x8 hb) {
  u64x2 q = __builtin_bit_cast(u64x2, hb);
  st8_agent((unsigned long long*)dst, q[0]);
  st8_agent((unsigned long long*)dst + 1, q[1]);
}

// ---- sentinel-poll a HALF-tile row-group: 8 chunks of 16B (rows = one l15
// row of a [16][1024] slab), rowbase = tile + laneoff (+ m*16*HID).
// Data IS the flag: ready when no dword == 0xAAAAAAAA (P[false-ready]~1e-30
// for bf16/f16 activations). Liveness == the proven agent flag mechanism.
__device__ __forceinline__ void tile_poll8(const unsigned short* rowbase, u16x8 (&Af)[8]) {
  const unsigned long long* b8 = (const unsigned long long*)rowbase;
  for (;;) {
    unsigned long long v[16];
#pragma unroll
    for (int ks = 0; ks < 8; ++ks) {
      v[2 * ks]     = ld8_agent(b8 + ks * 8);
      v[2 * ks + 1] = ld8_agent(b8 + ks * 8 + 1);
    }
    int good = 1;
#pragma unroll
    for (int c = 0; c < 16; ++c)
      good &= ((unsigned)v[c] != SENT32) & ((unsigned)(v[c] >> 32) != SENT32);
    if (__all(good)) {
#pragma unroll
      for (int ks = 0; ks < 8; ++ks) {
        u64x2 q; q[0] = v[2 * ks]; q[1] = v[2 * ks + 1];
        Af[ks] = __builtin_bit_cast(u16x8, q);
      }
      return;
    }
    __builtin_amdgcn_s_sleep(1);
  }
}

__global__ void init_kernel(int* boot) {
  if (threadIdx.x < 17) boot[threadIdx.x] = (threadIdx.x == 16) ? -1 : 0;
}

// -------- xproj GEMM (layer 0): xps[s*32+b][h] = x[b][s][:]·W_ih0^T + b_ih0 + b_hh0 (f16 out)
__global__ __launch_bounds__(256, 2)
void xproj_gemm(const float* __restrict__ X,
                const float* __restrict__ W,
                const float* __restrict__ bih,
                const float* __restrict__ bhh,
                unsigned short* __restrict__ out)
{
  __shared__ unsigned short sA[128 * 32];
  __shared__ unsigned short sB[128 * 32];
  const int tid  = threadIdx.x;
  const int lane = tid & 63;
  const int wave = tid >> 6;
  const int wm = wave >> 1, wn = wave & 1;
  const int bm = blockIdx.x >> 3;
  const int bn = blockIdx.x & 7;
  const int l15 = lane & 15;
  const int koff = (lane >> 4) * 8;
  const int srow = tid >> 2;
  const int skc  = (tid & 3) * 8;

  f32x4 acc[4][4];
#pragma unroll
  for (int i = 0; i < 4; ++i)
#pragma unroll
    for (int j = 0; j < 4; ++j) acc[i][j] = (f32x4)0.f;

  for (int k0 = 0; k0 < HID; k0 += 32) {
#pragma unroll
    for (int r = 0; r < 2; ++r) {
      int row = r * 64 + srow;
      int Mrow = bm * 128 + row;
      const float* src = X + ((size_t)(Mrow & 31) * SEQL + (Mrow >> 5)) * HID + k0 + skc;
      float4 a = ((const float4*)src)[0];
      float4 b = ((const float4*)src)[1];
      u16x8 av;
      av[0]=f2bf(a.x); av[1]=f2bf(a.y); av[2]=f2bf(a.z); av[3]=f2bf(a.w);
      av[4]=f2bf(b.x); av[5]=f2bf(b.y); av[6]=f2bf(b.z); av[7]=f2bf(b.w);
      *(u16x8*)&sA[row * 32 + skc] = av;

      const float* wsrc = W + (size_t)(bn * 128 + row) * HID + k0 + skc;
      float4 wa = ((const float4*)wsrc)[0];
      float4 wb = ((const float4*)wsrc)[1];
      u16x8 wv;
      wv[0]=f2bf(wa.x); wv[1]=f2bf(wa.y); wv[2]=f2bf(wa.z); wv[3]=f2bf(wa.w);
      wv[4]=f2bf(wb.x); wv[5]=f2bf(wb.y); wv[6]=f2bf(wb.z); wv[7]=f2bf(wb.w);
      *(u16x8*)&sB[row * 32 + skc] = wv;
    }
    __syncthreads();

    u16x8 af[4], bfr[4];
#pragma unroll
    for (int mt = 0; mt < 4; ++mt)
      af[mt] = *(const u16x8*)&sA[(wm * 64 + mt * 16 + l15) * 32 + koff];
#pragma unroll
    for (int nt = 0; nt < 4; ++nt)
      bfr[nt] = *(const u16x8*)&sB[(wn * 64 + nt * 16 + l15) * 32 + koff];
#pragma unroll
    for (int mt = 0; mt < 4; ++mt)
#pragma unroll
      for (int nt = 0; nt < 4; ++nt)
        acc[mt][nt] = mfma16(af[mt], bfr[nt], acc[mt][nt]);
    __syncthreads();
  }

#pragma unroll
  for (int nt = 0; nt < 4; ++nt) {
    int colg = bn * 128 + wn * 64 + nt * 16 + l15;
    float bias = bih[colg] + bhh[colg];
#pragma unroll
    for (int mt = 0; mt < 4; ++mt) {
#pragma unroll
      for (int i = 0; i < 4; ++i) {
        int rowg = bm * 128 + wm * 64 + mt * 16 + (lane >> 4) * 4 + i;
        out[(size_t)rowg * HID + colg] = f2h(acc[mt][nt][i] + bias);
      }
    }
  }
}

// -------- fused 2-stage SENTINEL-DATAFLOW scan on ONE XCD: no flags at all --------
// stage A (role 0..15):  h0[t] = tanh(xps[t] + h0[t-1]·W_hh0^T) -> h0b (agent 8B stores)
// stage B (role 16..31): h1[t] = tanh(h0[t]·W_ih1^T + b1 + h1[t-1]·W_hh1^T) -> h1b + out
// Consumers poll the data itself via agent atomic loads (sentinel 0xAA).
__global__ __launch_bounds__(256, 1)
void fused_scan(const unsigned short* __restrict__ xps,   // f16, read-only
                const float* __restrict__ whh0,
                const float* __restrict__ wih1,
                const float* __restrict__ whh1,
                const float* __restrict__ bih1,
                const float* __restrict__ bhh1,
                unsigned short* __restrict__ h0b,
                unsigned short* __restrict__ h1b,
                float* __restrict__ out,
                int* __restrict__ boot)
{
  const int tid  = threadIdx.x;

  // ---- XCD-colocation bootstrap (proven rounds 5-15) ----
  __shared__ int s_role;
  if (tid == 0) {
    unsigned xcc;
    asm volatile("s_getreg_b32 %0, hwreg(HW_REG_XCC_ID)" : "=s"(xcc));
    xcc &= 15u;
    int slot = __hip_atomic_fetch_add(&boot[(int)xcc], 1, __ATOMIC_RELAXED,
                                      __HIP_MEMORY_SCOPE_AGENT);
    if (slot == NWORK - 1) {
      int exp = -1;
      __hip_atomic_compare_exchange_strong(&boot[16], &exp, (int)xcc,
          __ATOMIC_RELAXED, __ATOMIC_RELAXED, __HIP_MEMORY_SCOPE_AGENT);
    }
    int ch;
    while ((ch = __hip_atomic_load(&boot[16], __ATOMIC_RELAXED,
                                   __HIP_MEMORY_SCOPE_AGENT)) < 0)
      __builtin_amdgcn_s_sleep(8);
    s_role = ((int)xcc == ch && slot < NWORK) ? slot : -1;
  }
  __syncthreads();
  const int role = s_role;
  if (role < 0) return;

  const int lane = tid & 63;
  const int wave = tid >> 6;
  const int l15  = lane & 15;
  const int l4   = lane >> 4;
  const int wg    = role & 15;
  const int col0  = wg * 64;
  const int kbase = wave * 256;
  const int frow  = tid >> 3;        // 0..31 batch row (finish phase)
  const int fcb   = (tid & 7) * 8;   // col offset within 64-col slice
  const int laneoff = l15 * HID + kbase + l4 * 8;

  __shared__ float red[4][32][68];

  if (role < 16) {
    // ---------------- stage A ----------------
    u16x8 Bf[4][8];
#pragma unroll
    for (int nt = 0; nt < 4; ++nt)
#pragma unroll
      for (int ks = 0; ks < 8; ++ks) {
        const float* src = whh0 + (size_t)(col0 + nt * 16 + l15) * HID + kbase + ks * 32 + l4 * 8;
        float4 a = ((const float4*)src)[0];
        float4 b = ((const float4*)src)[1];
        u16x8 v;
        v[0]=f2bf(a.x); v[1]=f2bf(a.y); v[2]=f2bf(a.z); v[3]=f2bf(a.w);
        v[4]=f2bf(b.x); v[5]=f2bf(b.y); v[6]=f2bf(b.z); v[7]=f2bf(b.w);
        Bf[nt][ks] = v;
      }

    u16x8 xh = *(const u16x8*)(xps + (size_t)frow * HID + col0 + fcb);

    for (int t = 0; t < SEQL; ++t) {
      f32x4 acc[2][4];
#pragma unroll
      for (int m = 0; m < 2; ++m)
#pragma unroll
        for (int n = 0; n < 4; ++n) acc[m][n] = (f32x4)0.f;
      if (t > 0) {
        const unsigned short* hp = h0b + (size_t)(t - 1) * (BSZ * HID) + laneoff;
#pragma unroll
        for (int m = 0; m < 2; ++m) {
          u16x8 Af[8];
          tile_poll8(hp + m * 16 * HID, Af);
#pragma unroll
          for (int ks = 0; ks < 8; ++ks)
#pragma unroll
            for (int n = 0; n < 4; ++n)
              acc[m][n] = mfma16(Af[ks], Bf[n][ks], acc[m][n]);
        }
      }
#pragma unroll
      for (int m = 0; m < 2; ++m)
#pragma unroll
        for (int n = 0; n < 4; ++n)
#pragma unroll
          for (int q = 0; q < 4; ++q)
            red[wave][m * 16 + l4 * 4 + q][n * 16 + l15] = acc[m][n][q];
      __syncthreads();
      float hv[8];
#pragma unroll
      for (int jj = 0; jj < 2; ++jj) {
        float4 r0 = *(const float4*)&red[0][frow][fcb + jj * 4];
        float4 r1 = *(const float4*)&red[1][frow][fcb + jj * 4];
        float4 r2 = *(const float4*)&red[2][frow][fcb + jj * 4];
        float4 r3 = *(const float4*)&red[3][frow][fcb + jj * 4];
        hv[jj*4+0] = r0.x + r1.x + r2.x + r3.x;
        hv[jj*4+1] = r0.y + r1.y + r2.y + r3.y;
        hv[jj*4+2] = r0.z + r1.z + r2.z + r3.z;
        hv[jj*4+3] = r0.w + r1.w + r2.w + r3.w;
      }
#pragma unroll
      for (int j = 0; j < 8; ++j) hv[j] = tanh_fast(hv[j] + h2f((unsigned short)xh[j]));
      u16x8 hb;
#pragma unroll
      for (int j = 0; j < 8; ++j) hb[j] = f2bf(hv[j]);
      // publish h0[t] slice: agent 8B stores (data IS the flag)
      st_frag(h0b + (size_t)t * (BSZ * HID) + (size_t)frow * HID + col0 + fcb, hb);
      if (t == SEQL - 1) {
        float* o = out + HN_OFF + (size_t)frow * HID + col0 + fcb;
        ((float4*)o)[0] = make_float4(hv[0], hv[1], hv[2], hv[3]);
        ((float4*)o)[1] = make_float4(hv[4], hv[5], hv[6], hv[7]);
      } else {
        xh = *(const u16x8*)(xps + ((size_t)(t + 1) * BSZ + frow) * HID + col0 + fcb);
      }
      __syncthreads();   // guard red reuse across steps
    }
  } else {
    // ---------------- stage B (merged xproj1 + layer-1 recurrence) ----------------
    u16x8 Bih[4][8], Bhh[4][8];
#pragma unroll
    for (int nt = 0; nt < 4; ++nt)
#pragma unroll
      for (int ks = 0; ks < 8; ++ks) {
        const float* s1 = wih1 + (size_t)(col0 + nt * 16 + l15) * HID + kbase + ks * 32 + l4 * 8;
        float4 a = ((const float4*)s1)[0];
        float4 b = ((const float4*)s1)[1];
        u16x8 v;
        v[0]=f2bf(a.x); v[1]=f2bf(a.y); v[2]=f2bf(a.z); v[3]=f2bf(a.w);
        v[4]=f2bf(b.x); v[5]=f2bf(b.y); v[6]=f2bf(b.z); v[7]=f2bf(b.w);
        Bih[nt][ks] = v;
        const float* s2 = whh1 + (size_t)(col0 + nt * 16 + l15) * HID + kbase + ks * 32 + l4 * 8;
        float4 c = ((const float4*)s2)[0];
        float4 d = ((const float4*)s2)[1];
        u16x8 w;
        w[0]=f2bf(c.x); w[1]=f2bf(c.y); w[2]=f2bf(c.z); w[3]=f2bf(c.w);
        w[4]=f2bf(d.x); w[5]=f2bf(d.y); w[6]=f2bf(d.z); w[7]=f2bf(d.w);
        Bhh[nt][ks] = w;
      }
    float bia[8];
#pragma unroll
    for (int j = 0; j < 8; ++j)
      bia[j] = bih1[col0 + fcb + j] + bhh1[col0 + fcb + j];

    for (int t = 0; t < SEQL; ++t) {
      f32x4 acc[2][4];
#pragma unroll
      for (int m = 0; m < 2; ++m)
#pragma unroll
        for (int n = 0; n < 4; ++n) acc[m][n] = (f32x4)0.f;
      // xproj1 contribution: poll h0[t]
      {
        const unsigned short* hp = h0b + (size_t)t * (BSZ * HID) + laneoff;
#pragma unroll
        for (int m = 0; m < 2; ++m) {
          u16x8 Af[8];
          tile_poll8(hp + m * 16 * HID, Af);
#pragma unroll
          for (int ks = 0; ks < 8; ++ks)
#pragma unroll
            for (int n = 0; n < 4; ++n)
              acc[m][n] = mfma16(Af[ks], Bih[n][ks], acc[m][n]);
        }
      }
      // recurrence contribution: poll h1[t-1]
      if (t > 0) {
        const unsigned short* hp = h1b + (size_t)(t - 1) * (BSZ * HID) + laneoff;
#pragma unroll
        for (int m = 0; m < 2; ++m) {
          u16x8 Af[8];
          tile_poll8(hp + m * 16 * HID, Af);
#pragma unroll
          for (int ks = 0; ks < 8; ++ks)
#pragma unroll
            for (int n = 0; n < 4; ++n)
              acc[m][n] = mfma16(Af[ks], Bhh[n][ks], acc[m][n]);
        }
      }
#pragma unroll
      for (int m = 0; m < 2; ++m)
#pragma unroll
        for (int n = 0; n < 4; ++n)
#pragma unroll
          for (int q = 0; q < 4; ++q)
            red[wave][m * 16 + l4 * 4 + q][n * 16 + l15] = acc[m][n][q];
      __syncthreads();
      float hv[8];
#pragma unroll
      for (int jj = 0; jj < 2; ++jj) {
        float4 r0 = *(const float4*)&red[0][frow][fcb + jj * 4];
        float4 r1 = *(const float4*)&red[1][frow][fcb + jj * 4];
        float4 r2 = *(const float4*)&red[2][frow][fcb + jj * 4];
        float4 r3 = *(const float4*)&red[3][frow][fcb + jj * 4];
        hv[jj*4+0] = r0.x + r1.x + r2.x + r3.x;
        hv[jj*4+1] = r0.y + r1.y + r2.y + r3.y;
        hv[jj*4+2] = r0.z + r1.z + r2.z + r3.z;
        hv[jj*4+3] = r0.w + r1.w + r2.w + r3.w;
      }
#pragma unroll
      for (int j = 0; j < 8; ++j) hv[j] = tanh_fast(hv[j] + bia[j]);
      u16x8 hb;
#pragma unroll
      for (int j = 0; j < 8; ++j) hb[j] = f2bf(hv[j]);
      st_frag(h1b + (size_t)t * (BSZ * HID) + (size_t)frow * HID + col0 + fcb, hb);
      float* op = out + ((size_t)frow * SEQL + t) * HID + col0 + fcb;
      ((float4*)op)[0] = make_float4(hv[0], hv[1], hv[2], hv[3]);
      ((float4*)op)[1] = make_float4(hv[4], hv[5], hv[6], hv[7]);
      if (t == SEQL - 1) {
        float* o = out + HN_OFF + BSZ * HID + (size_t)frow * HID + col0 + fcb;
        ((float4*)o)[0] = make_float4(hv[0], hv[1], hv[2], hv[3]);
        ((float4*)o)[1] = make_float4(hv[4], hv[5], hv[6], hv[7]);
      }
      __syncthreads();   // guard red reuse across steps
    }
  }
}

extern "C" void kernel_launch(void* const* d_in, const int* in_sizes, int n_in,
                              void* d_out, int out_size, void* d_ws, size_t ws_size,
                              hipStream_t stream) {
  const float* x    = (const float*)d_in[0];
  const float* w_ih = (const float*)d_in[1];
  const float* w_hh = (const float*)d_in[2];
  const float* b_ih = (const float*)d_in[3];
  const float* b_hh = (const float*)d_in[4];
  float* out = (float*)d_out;
  char* ws = (char*)d_ws;

  unsigned short* xps = (unsigned short*)(ws + XPS_OFF);
  unsigned short* h0b = (unsigned short*)(ws + H0B_OFF);
  unsigned short* h1b = (unsigned short*)(ws + H1B_OFF);
  int* boot           = (int*)(ws + BOOT_OFF);

  // re-arm sentinels in h0b+h1b every launch (r4 proved memsetAsync captures;
  // SDMA writes are stream-ordered and visible to agent atomic loads)
  hipMemsetAsync(ws + H0B_OFF, 0xAA, 67108864u, stream);

  init_kernel<<<1, 64, 0, stream>>>(boot);
  xproj_gemm<<<1024, 256, 0, stream>>>(x, w_ih, b_ih, b_hh, xps);
  fused_scan<<<NLAUNCH, 256, 0, stream>>>(xps, w_hh,
      w_ih + (size_t)HID * HID, w_hh + (size_t)HID * HID,
      b_ih + HID, b_hh + HID, h0b, h1b, out, boot);
}

// Round 17
// 3401.096 us; speedup vs baseline: 3.1637x; 1.3829x over previous
//
#include <hip/hip_runtime.h>

#define SEQL 512
#define BSZ  32
#define HID  1024
#define NWORK 48
#define NLAUNCH 384
#define HN_OFF 16777216   // 32*512*1024

// ws layout (bytes): xps f16 [512][32][1024] @0 (32MB, overwritten in place with xp1);
// h0b bf16 @32MB (32MB); h1b bf16 @64MB (32MB); flags @96MB (3*512*16 u32 = 96KB);
// boot @96MB+128KB (18 ints: [0..15] per-XCD arrival, [16] elected XCD, [17] done ctr).
#define XPS_OFF 0u
#define H0B_OFF 33554432u
#define H1B_OFF 67108864u
#define FLG_OFF 100663296u
#define BOOT_OFF 100794368u

using f32x4  = __attribute__((ext_vector_type(4))) float;
using u16x8  = __attribute__((ext_vector_type(8))) unsigned short;
using u32x4  = __attribute__((ext_vector_type(4))) unsigned int;
using bf16x8 = __attribute__((ext_vector_type(8))) __bf16;

__device__ __forceinline__ f32x4 mfma16(u16x8 a, u16x8 b, f32x4 c) {
  return __builtin_amdgcn_mfma_f32_16x16x32_bf16(
      __builtin_bit_cast(bf16x8, a), __builtin_bit_cast(bf16x8, b), c, 0, 0, 0);
}

__device__ __forceinline__ unsigned short f2bf(float f) {
  unsigned u = __builtin_bit_cast(unsigned, f);
  u += 0x7fffu + ((u >> 16) & 1u);
  return (unsigned short)(u >> 16);
}
__device__ __forceinline__ unsigned short f2h(float f) {
  _Float16 h = (_Float16)f;
  return __builtin_bit_cast(unsigned short, h);
}
__device__ __forceinline__ float h2f(unsigned short u) {
  return (float)__builtin_bit_cast(_Float16, u);
}

__device__ __forceinline__ float tanh_fast(float x) {
  float cx = fminf(fmaxf(x, -15.f), 15.f);
  float e = __expf(2.f * cx);
  return __fdividef(e - 1.f, e + 1.f);
}

// 16B sc0 load (8 f16/bf16 elements) — only for the multi-writer xps line
__device__ __forceinline__ u16x8 ld8h_sc0(const void* p) {
  u32x4 r;
  asm volatile("global_load_dwordx4 %0, %1, off sc0\n\ts_waitcnt vmcnt(0)"
               : "=&v"(r) : "v"(p) : "memory");
  return __builtin_bit_cast(u16x8, r);
}

// ---- flags: agent-scope atomics (proven rounds 2-3-5-7-8-9-10)
__device__ __forceinline__ void flag_set(unsigned* p) {
  __hip_atomic_store(p, 1u, __ATOMIC_RELAXED, __HIP_MEMORY_SCOPE_AGENT);
}
__device__ __forceinline__ unsigned flag_get(const unsigned* p) {
  return __hip_atomic_load(p, __ATOMIC_RELAXED, __HIP_MEMORY_SCOPE_AGENT);
}

// WG-level wait (round-8 version, unchanged): wave 0 polls the coalesced 64B
// flag line with s_sleep backoff; __syncthreads releases the other waves.
__device__ __forceinline__ void wg_wait16(const unsigned* flt, int tid) {
  if (tid < 64) {
    const unsigned* p = flt + (tid & 15);
    while (!__all(flag_get(p) != 0u)) __builtin_amdgcn_s_sleep(1);
  }
  __syncthreads();
}
__device__ __forceinline__ void wg_wait1(const unsigned* p, int tid) {
  if (tid < 64) {
    while (!__all(flag_get(p) != 0u)) __builtin_amdgcn_s_sleep(1);
  }
  __syncthreads();
}

__global__ void init_kernel(unsigned* flg, int* boot) {
  int i = blockIdx.x * 256 + threadIdx.x;   // 96*256 = 24576 = 3*512*16
  flg[i] = 0u;
  if (blockIdx.x == 0 && threadIdx.x < 18)
    boot[threadIdx.x] = (threadIdx.x == 16) ? -1 : 0;
}

// -------- xproj GEMM (layer 0): xps[s*32+b][h] = x[b][s][:]·W_ih0^T + b_ih0 + b_hh0 (f16 out)
__global__ __launch_bounds__(256, 2)
void xproj_gemm(const float* __restrict__ X,
                const float* __restrict__ W,
                const float* __restrict__ bih,
                const float* __restrict__ bhh,
                unsigned short* __restrict__ out)
{
  __shared__ unsigned short sA[128 * 32];
  __shared__ unsigned short sB[128 * 32];
  const int tid  = threadIdx.x;
  const int lane = tid & 63;
  const int wave = tid >> 6;
  const int wm = wave >> 1, wn = wave & 1;
  const int bm = blockIdx.x >> 3;
  const int bn = blockIdx.x & 7;
  const int l15 = lane & 15;
  const int koff = (lane >> 4) * 8;
  const int srow = tid >> 2;
  const int skc  = (tid & 3) * 8;

  f32x4 acc[4][4];
#pragma unroll
  for (int i = 0; i < 4; ++i)
#pragma unroll
    for (int j = 0; j < 4; ++j) acc[i][j] = (f32x4)0.f;

  for (int k0 = 0; k0 < HID; k0 += 32) {
#pragma unroll
    for (int r = 0; r < 2; ++r) {
      int row = r * 64 + srow;
      int Mrow = bm * 128 + row;
      const float* src = X + ((size_t)(Mrow & 31) * SEQL + (Mrow >> 5)) * HID + k0 + skc;
      float4 a = ((const float4*)src)[0];
      float4 b = ((const float4*)src)[1];
      u16x8 av;
      av[0]=f2bf(a.x); av[1]=f2bf(a.y); av[2]=f2bf(a.z); av[3]=f2bf(a.w);
      av[4]=f2bf(b.x); av[5]=f2bf(b.y); av[6]=f2bf(b.z); av[7]=f2bf(b.w);
      *(u16x8*)&sA[row * 32 + skc] = av;

      const float* wsrc = W + (size_t)(bn * 128 + row) * HID + k0 + skc;
      float4 wa = ((const float4*)wsrc)[0];
      float4 wb = ((const float4*)wsrc)[1];
      u16x8 wv;
      wv[0]=f2bf(wa.x); wv[1]=f2bf(wa.y); wv[2]=f2bf(wa.z); wv[3]=f2bf(wa.w);
      wv[4]=f2bf(wb.x); wv[5]=f2bf(wb.y); wv[6]=f2bf(wb.z); wv[7]=f2bf(wb.w);
      *(u16x8*)&sB[row * 32 + skc] = wv;
    }
    __syncthreads();

    u16x8 af[4], bfr[4];
#pragma unroll
    for (int mt = 0; mt < 4; ++mt)
      af[mt] = *(const u16x8*)&sA[(wm * 64 + mt * 16 + l15) * 32 + koff];
#pragma unroll
    for (int nt = 0; nt < 4; ++nt)
      bfr[nt] = *(const u16x8*)&sB[(wn * 64 + nt * 16 + l15) * 32 + koff];
#pragma unroll
    for (int mt = 0; mt < 4; ++mt)
#pragma unroll
      for (int nt = 0; nt < 4; ++nt)
        acc[mt][nt] = mfma16(af[mt], bfr[nt], acc[mt][nt]);
    __syncthreads();
  }

#pragma unroll
  for (int nt = 0; nt < 4; ++nt) {
    int colg = bn * 128 + wn * 64 + nt * 16 + l15;
    float bias = bih[colg] + bhh[colg];
#pragma unroll
    for (int mt = 0; mt < 4; ++mt) {
#pragma unroll
      for (int i = 0; i < 4; ++i) {
        int rowg = bm * 128 + wm * 64 + mt * 16 + (lane >> 4) * 4 + i;
        out[(size_t)rowg * HID + colg] = f2h(acc[mt][nt][i] + bias);
      }
    }
  }
}

// -------- fused 3-stage scan on ONE XCD (round-8 protocol; plain h-tile loads)
//          + FABRIC heaters: streaming HBM readers on the other XCDs --------
// S0 (role 0..15):  h0[t] = tanh(xps[t] + h0[t-1]·W_hh0^T) -> h0b, flag flA
// S1 (role 16..31): xp1[t] = h0[t]·W_ih1^T + b1 -> xps[t] slot (f16), flag flB
// S2 (role 32..47): h1[t] = tanh(xp1[t] + h1[t-1]·W_hh1^T) -> h1b + out, flag flC
__global__ __launch_bounds__(256, 2)
void fused_scan(unsigned short* __restrict__ xps,   // f16 [512][32][1024], in-place xp1
                const float* __restrict__ xheat,    // x input: 64MB read-only (heater fuel)
                const float* __restrict__ whh0,
                const float* __restrict__ wih1,
                const float* __restrict__ whh1,
                const float* __restrict__ bih1,
                const float* __restrict__ bhh1,
                unsigned short* __restrict__ h0b,
                unsigned short* __restrict__ h1b,
                float* __restrict__ out,
                unsigned* __restrict__ flg,
                int* __restrict__ boot)
{
  const int tid  = threadIdx.x;

  // ---- XCD-colocation bootstrap (proven rounds 5-12) ----
  __shared__ int s_role;
  if (tid == 0) {
    unsigned xcc;
    asm volatile("s_getreg_b32 %0, hwreg(HW_REG_XCC_ID)" : "=s"(xcc));
    xcc &= 15u;
    int slot = __hip_atomic_fetch_add(&boot[(int)xcc], 1, __ATOMIC_RELAXED,
                                      __HIP_MEMORY_SCOPE_AGENT);
    if (slot == NWORK - 1) {
      int exp = -1;
      __hip_atomic_compare_exchange_strong(&boot[16], &exp, (int)xcc,
          __ATOMIC_RELAXED, __ATOMIC_RELAXED, __HIP_MEMORY_SCOPE_AGENT);
    }
    int ch;
    while ((ch = __hip_atomic_load(&boot[16], __ATOMIC_RELAXED,
                                   __HIP_MEMORY_SCOPE_AGENT)) < 0)
      __builtin_amdgcn_s_sleep(8);
    // chosen XCD: slot<48 worker else exit; other XCDs: slot<8 heater else exit
    s_role = ((int)xcc == ch) ? (slot < NWORK ? slot : -1)
                              : (slot < 8 ? -2 : -1);
  }
  __syncthreads();
  const int role = s_role;
  if (role == -1) return;

  if (role == -2) {
    // ---- bounded FABRIC heater: stream-read the 64MB x buffer (read-only).
    const char* base = (const char*)xheat;
    float4 acc0 = make_float4(0.f, 0.f, 0.f, 0.f);
    unsigned seq = (unsigned)(blockIdx.x * 2654435761u);
    for (int it = 0; it < 20000; ++it) {
      unsigned chunk = (seq = seq * 1664525u + 1013904223u) & 4095u;
      const float4* p = (const float4*)(base + (size_t)chunk * 16384u) + tid;
      float4 v0 = p[0];
      float4 v1 = p[256];
      float4 v2 = p[512];
      float4 v3 = p[768];
      acc0.x += v0.x + v1.x + v2.x + v3.x;
      acc0.y += v0.y + v1.y + v2.y + v3.y;
      acc0.z += v0.z + v1.z;
      acc0.w += v3.w;
      if (__hip_atomic_load(&boot[17], __ATOMIC_RELAXED,
                            __HIP_MEMORY_SCOPE_AGENT) >= NWORK)
        break;
    }
    asm volatile("" :: "v"(acc0.x), "v"(acc0.y), "v"(acc0.z), "v"(acc0.w));
    return;
  }

  const int lane = tid & 63;
  const int wave = tid >> 6;
  const int l15  = lane & 15;
  const int l4   = lane >> 4;
  const int stage = role >> 4;
  const int wg    = role & 15;
  const int col0  = wg * 64;
  const int kbase = wave * 256;
  const int frow  = tid >> 3;        // 0..31 batch row (finish phase)
  const int fcb   = (tid & 7) * 8;   // col offset within 64-col slice

  unsigned* flA = flg;
  unsigned* flB = flg + SEQL * 16;
  unsigned* flC = flg + 2 * SEQL * 16;

  __shared__ float red[4][32][68];

  // persistent weight fragments (f32 -> bf16), 128 VGPRs
  const float* Wsl = (stage == 0) ? whh0 : (stage == 1) ? wih1 : whh1;
  u16x8 Bf[4][8];
#pragma unroll
  for (int nt = 0; nt < 4; ++nt)
#pragma unroll
    for (int ks = 0; ks < 8; ++ks) {
      const float* src = Wsl + (size_t)(col0 + nt * 16 + l15) * HID + kbase + ks * 32 + l4 * 8;
      float4 a = ((const float4*)src)[0];
      float4 b = ((const float4*)src)[1];
      u16x8 v;
      v[0]=f2bf(a.x); v[1]=f2bf(a.y); v[2]=f2bf(a.z); v[3]=f2bf(a.w);
      v[4]=f2bf(b.x); v[5]=f2bf(b.y); v[6]=f2bf(b.z); v[7]=f2bf(b.w);
      Bf[nt][ks] = v;
    }

  if (stage == 0) {
    u16x8 xh = *(const u16x8*)(xps + (size_t)frow * HID + col0 + fcb);
    for (int t = 0; t < SEQL; ++t) {
      f32x4 acc[2][4];
#pragma unroll
      for (int m = 0; m < 2; ++m)
#pragma unroll
        for (int n = 0; n < 4; ++n) acc[m][n] = (f32x4)0.f;
      if (t > 0) {
        wg_wait16(flA + (t - 1) * 16, tid);
        const unsigned short* hp = h0b + (size_t)(t - 1) * (BSZ * HID);
        u16x8 Af[2][8];
#pragma unroll
        for (int m = 0; m < 2; ++m)
#pragma unroll
          for (int ks = 0; ks < 8; ++ks)
            Af[m][ks] = *(const u16x8*)(hp + (size_t)(m * 16 + l15) * HID + kbase + ks * 32 + l4 * 8);
#pragma unroll
        for (int ks = 0; ks < 8; ++ks)
#pragma unroll
          for (int m = 0; m < 2; ++m)
#pragma unroll
            for (int n = 0; n < 4; ++n)
              acc[m][n] = mfma16(Af[m][ks], Bf[n][ks], acc[m][n]);
      }
#pragma unroll
      for (int m = 0; m < 2; ++m)
#pragma unroll
        for (int n = 0; n < 4; ++n)
#pragma unroll
          for (int q = 0; q < 4; ++q)
            red[wave][m * 16 + l4 * 4 + q][n * 16 + l15] = acc[m][n][q];
      __syncthreads();
      float hv[8];
#pragma unroll
      for (int jj = 0; jj < 2; ++jj) {
        float4 r0 = *(const float4*)&red[0][frow][fcb + jj * 4];
        float4 r1 = *(const float4*)&red[1][frow][fcb + jj * 4];
        float4 r2 = *(const float4*)&red[2][frow][fcb + jj * 4];
        float4 r3 = *(const float4*)&red[3][frow][fcb + jj * 4];
        hv[jj*4+0] = r0.x + r1.x + r2.x + r3.x;
        hv[jj*4+1] = r0.y + r1.y + r2.y + r3.y;
        hv[jj*4+2] = r0.z + r1.z + r2.z + r3.z;
        hv[jj*4+3] = r0.w + r1.w + r2.w + r3.w;
      }
#pragma unroll
      for (int j = 0; j < 8; ++j) hv[j] = tanh_fast(hv[j] + h2f((unsigned short)xh[j]));
      u16x8 hb;
#pragma unroll
      for (int j = 0; j < 8; ++j) hb[j] = f2bf(hv[j]);
      *(u16x8*)(h0b + (size_t)t * (BSZ * HID) + (size_t)frow * HID + col0 + fcb) = hb;
      if (t == SEQL - 1) {
        float* o = out + HN_OFF + (size_t)frow * HID + col0 + fcb;
        ((float4*)o)[0] = make_float4(hv[0], hv[1], hv[2], hv[3]);
        ((float4*)o)[1] = make_float4(hv[4], hv[5], hv[6], hv[7]);
      } else {
        xh = *(const u16x8*)(xps + ((size_t)(t + 1) * BSZ + frow) * HID + col0 + fcb);
      }
      asm volatile("s_waitcnt vmcnt(0)" ::: "memory");   // stores at L2 (coherence pt)
      __syncthreads();
      if (tid == 0) flag_set(&flA[t * 16 + wg]);
    }
  } else if (stage == 1) {
    float bia[8];
#pragma unroll
    for (int j = 0; j < 8; ++j)
      bia[j] = bih1[col0 + fcb + j] + bhh1[col0 + fcb + j];
    for (int t = 0; t < SEQL; ++t) {
      wg_wait16(flA + t * 16, tid);
      const unsigned short* hp = h0b + (size_t)t * (BSZ * HID);
      u16x8 Af[2][8];
#pragma unroll
      for (int m = 0; m < 2; ++m)
#pragma unroll
        for (int ks = 0; ks < 8; ++ks)
          Af[m][ks] = *(const u16x8*)(hp + (size_t)(m * 16 + l15) * HID + kbase + ks * 32 + l4 * 8);
      f32x4 acc[2][4];
#pragma unroll
      for (int m = 0; m < 2; ++m)
#pragma unroll
        for (int n = 0; n < 4; ++n) acc[m][n] = (f32x4)0.f;
#pragma unroll
      for (int ks = 0; ks < 8; ++ks)
#pragma unroll
        for (int m = 0; m < 2; ++m)
#pragma unroll
          for (int n = 0; n < 4; ++n)
            acc[m][n] = mfma16(Af[m][ks], Bf[n][ks], acc[m][n]);
#pragma unroll
      for (int m = 0; m < 2; ++m)
#pragma unroll
        for (int n = 0; n < 4; ++n)
#pragma unroll
          for (int q = 0; q < 4; ++q)
            red[wave][m * 16 + l4 * 4 + q][n * 16 + l15] = acc[m][n][q];
      __syncthreads();
      float sv[8];
#pragma unroll
      for (int jj = 0; jj < 2; ++jj) {
        float4 r0 = *(const float4*)&red[0][frow][fcb + jj * 4];
        float4 r1 = *(const float4*)&red[1][frow][fcb + jj * 4];
        float4 r2 = *(const float4*)&red[2][frow][fcb + jj * 4];
        float4 r3 = *(const float4*)&red[3][frow][fcb + jj * 4];
        sv[jj*4+0] = r0.x + r1.x + r2.x + r3.x;
        sv[jj*4+1] = r0.y + r1.y + r2.y + r3.y;
        sv[jj*4+2] = r0.z + r1.z + r2.z + r3.z;
        sv[jj*4+3] = r0.w + r1.w + r2.w + r3.w;
      }
      u16x8 xo;
#pragma unroll
      for (int j = 0; j < 8; ++j) xo[j] = f2h(sv[j] + bia[j]);
      *(u16x8*)(xps + ((size_t)t * BSZ + frow) * HID + col0 + fcb) = xo;
      asm volatile("s_waitcnt vmcnt(0)" ::: "memory");
      __syncthreads();
      if (tid == 0) flag_set(&flB[t * 16 + wg]);
    }
  } else {
    for (int t = 0; t < SEQL; ++t) {
      f32x4 acc[2][4];
#pragma unroll
      for (int m = 0; m < 2; ++m)
#pragma unroll
        for (int n = 0; n < 4; ++n) acc[m][n] = (f32x4)0.f;
      if (t > 0) {
        wg_wait16(flC + (t - 1) * 16, tid);
        const unsigned short* hp = h1b + (size_t)(t - 1) * (BSZ * HID);
        u16x8 Af[2][8];
#pragma unroll
        for (int m = 0; m < 2; ++m)
#pragma unroll
          for (int ks = 0; ks < 8; ++ks)
            Af[m][ks] = *(const u16x8*)(hp + (size_t)(m * 16 + l15) * HID + kbase + ks * 32 + l4 * 8);
#pragma unroll
        for (int ks = 0; ks < 8; ++ks)
#pragma unroll
          for (int m = 0; m < 2; ++m)
#pragma unroll
            for (int n = 0; n < 4; ++n)
              acc[m][n] = mfma16(Af[m][ks], Bf[n][ks], acc[m][n]);
      }
#pragma unroll
      for (int m = 0; m < 2; ++m)
#pragma unroll
        for (int n = 0; n < 4; ++n)
#pragma unroll
          for (int q = 0; q < 4; ++q)
            red[wave][m * 16 + l4 * 4 + q][n * 16 + l15] = acc[m][n][q];
      __syncthreads();
      wg_wait1(&flB[t * 16 + wg], tid);
      u16x8 xq = ld8h_sc0(xps + ((size_t)t * BSZ + frow) * HID + col0 + fcb);
      float hv[8];
#pragma unroll
      for (int jj = 0; jj < 2; ++jj) {
        float4 r0 = *(const float4*)&red[0][frow][fcb + jj * 4];
        float4 r1 = *(const float4*)&red[1][frow][fcb + jj * 4];
        float4 r2 = *(const float4*)&red[2][frow][fcb + jj * 4];
        float4 r3 = *(const float4*)&red[3][frow][fcb + jj * 4];
        hv[jj*4+0] = r0.x + r1.x + r2.x + r3.x;
        hv[jj*4+1] = r0.y + r1.y + r2.y + r3.y;
        hv[jj*4+2] = r0.z + r1.z + r2.z + r3.z;
        hv[jj*4+3] = r0.w + r1.w + r2.w + r3.w;
      }
#pragma unroll
      for (int j = 0; j < 8; ++j) hv[j] = tanh_fast(hv[j] + h2f((unsigned short)xq[j]));
      u16x8 hb;
#pragma unroll
      for (int j = 0; j < 8; ++j) hb[j] = f2bf(hv[j]);
      *(u16x8*)(h1b + (size_t)t * (BSZ * HID) + (size_t)frow * HID + col0 + fcb) = hb;
      float* op = out + ((size_t)frow * SEQL + t) * HID + col0 + fcb;
      ((float4*)op)[0] = make_float4(hv[0], hv[1], hv[2], hv[3]);
      ((float4*)op)[1] = make_float4(hv[4], hv[5], hv[6], hv[7]);
      if (t == SEQL - 1) {
        float* o = out + HN_OFF + BSZ * HID + (size_t)frow * HID + col0 + fcb;
        ((float4*)o)[0] = make_float4(hv[0], hv[1], hv[2], hv[3]);
        ((float4*)o)[1] = make_float4(hv[4], hv[5], hv[6], hv[7]);
      }
      asm volatile("s_waitcnt vmcnt(0)" ::: "memory");
      __syncthreads();
      if (tid == 0) flag_set(&flC[t * 16 + wg]);
    }
  }

  // worker done-signal for heater early-exit (all 48 worker WGs)
  if (tid == 0)
    __hip_atomic_fetch_add(&boot[17], 1, __ATOMIC_RELAXED, __HIP_MEMORY_SCOPE_AGENT);
}

extern "C" void kernel_launch(void* const* d_in, const int* in_sizes, int n_in,
                              void* d_out, int out_size, void* d_ws, size_t ws_size,
                              hipStream_t stream) {
  const float* x    = (const float*)d_in[0];
  const float* w_ih = (const float*)d_in[1];
  const float* w_hh = (const float*)d_in[2];
  const float* b_ih = (const float*)d_in[3];
  const float* b_hh = (const float*)d_in[4];
  float* out = (float*)d_out;
  char* ws = (char*)d_ws;

  unsigned short* xps = (unsigned short*)(ws + XPS_OFF);
  unsigned short* h0b = (unsigned short*)(ws + H0B_OFF);
  unsigned short* h1b = (unsigned short*)(ws + H1B_OFF);
  unsigned* flg       = (unsigned*)(ws + FLG_OFF);
  int* boot           = (int*)(ws + BOOT_OFF);

  init_kernel<<<96, 256, 0, stream>>>(flg, boot);
  xproj_gemm<<<1024, 256, 0, stream>>>(x, w_ih, b_ih, b_hh, xps);
  fused_scan<<<NLAUNCH, 256, 0, stream>>>(xps, x, w_hh,
      w_ih + (size_t)HID * HID, w_hh + (size_t)HID * HID,
      b_ih + HID, b_hh + HID, h0b, h1b, out, flg, boot);
}